// Round 1
// baseline (1070.887 us; speedup 1.0000x reference)
//
#include <hip/hip_runtime.h>

// ---------------------------------------------------------------------------
// TfmrAttention: B=2, S=2048, E=1024, H=16, D=64
// out = [attn_out (4,194,304 f32) | attn_weights (134,217,728 f32)]
// Strategy: bf16 MFMA (16x16x32) everywhere; weights region write-once.
// ---------------------------------------------------------------------------

typedef unsigned short u16;
typedef __attribute__((ext_vector_type(8))) short bf16x8;   // 8 bf16 = 4 VGPRs
typedef __attribute__((ext_vector_type(4))) float f32x4;
typedef __attribute__((ext_vector_type(4))) unsigned short u16x4;

#define MFMA(a, b, c) __builtin_amdgcn_mfma_f32_16x16x32_bf16((a), (b), (c), 0, 0, 0)

__device__ __forceinline__ u16 f2bf(float f) {          // RNE fp32->bf16
  unsigned u = __builtin_bit_cast(unsigned, f);
  u += 0x7FFFu + ((u >> 16) & 1u);
  return (u16)(u >> 16);
}
__device__ __forceinline__ float E2(float x) { return __builtin_amdgcn_exp2f(x); }

// 0.125 * log2(e): fold 1/sqrt(64) and natural->base2 exp into Q
#define QSCALE 0.18033688011112042f

// ---- cast fp32 -> bf16, 4 elems/thread ------------------------------------
__global__ __launch_bounds__(256) void k_cast(const float* __restrict__ in,
                                              u16* __restrict__ out, int n) {
  int i = (blockIdx.x * 256 + threadIdx.x) * 4;
  if (i + 3 < n) {
    float4 v = *(const float4*)(in + i);
    u16x4 o = { f2bf(v.x), f2bf(v.y), f2bf(v.z), f2bf(v.w) };
    *(u16x4*)(out + i) = o;
  }
}

// ---- transpose + cast: W[Kd][Nd] fp32 -> Wt[Nd][Kd] bf16 -------------------
__global__ __launch_bounds__(256) void k_transpose_cast(const float* __restrict__ in,
                                                        u16* __restrict__ out,
                                                        int Kd, int Nd) {
  __shared__ float tile[64][65];
  int n0 = blockIdx.x * 64, k0 = blockIdx.y * 64;
  int t = threadIdx.x, col = t & 63, r4 = t >> 6;
#pragma unroll
  for (int ph = 0; ph < 16; ++ph) {
    int row = ph * 4 + r4;                                   // tile[k_local][n_local]
    tile[row][col] = in[(size_t)(k0 + row) * Nd + n0 + col];
  }
  __syncthreads();
#pragma unroll
  for (int ph = 0; ph < 16; ++ph) {
    int row = ph * 4 + r4;                                   // out[n0+row][k0+col]
    out[(size_t)(n0 + row) * Kd + k0 + col] = f2bf(tile[col][row]);
  }
}

// ---- transpose bf16: V[bh][2048][64] -> Vt[bh][64][2048] -------------------
__global__ __launch_bounds__(256) void k_transpose_v(const u16* __restrict__ V,
                                                     u16* __restrict__ Vt) {
  __shared__ u16 tile[64][65];
  int bh = blockIdx.y, s0 = blockIdx.x * 64;
  int t = threadIdx.x, col = t & 63, r4 = t >> 6;
#pragma unroll
  for (int ph = 0; ph < 16; ++ph) {
    int row = ph * 4 + r4;                                   // tile[s_local][d]
    tile[row][col] = V[((size_t)bh * 2048 + s0 + row) * 64 + col];
  }
  __syncthreads();
#pragma unroll
  for (int ph = 0; ph < 16; ++ph) {
    int row = ph * 4 + r4;                                   // Vt[d=row][s0+col]
    Vt[((size_t)bh * 64 + row) * 2048 + s0 + col] = tile[col][row];
  }
}

// ---- GEMM1: hs[4096][1024] @ W[1024][3072] (+b) -> Q,K,V bf16 [b,h,s,d] ----
// 64x64 tile/block, 4 waves in 2x2, each wave 2x2 of 16x16 MFMA subtiles.
// All fragments loaded直接 from global (A row-major, Bt pre-transposed).
__global__ __launch_bounds__(256) void k_gemm_qkv(const u16* __restrict__ A,
                                                  const u16* __restrict__ Bt,
                                                  const float* __restrict__ bias,
                                                  u16* __restrict__ Q,
                                                  u16* __restrict__ Kp,
                                                  u16* __restrict__ V) {
  int t = threadIdx.x;
  int wave = t >> 6, lane = t & 63, quad = lane >> 4, l16 = lane & 15;
  int m_base = blockIdx.y * 64 + (wave >> 1) * 32;
  int n_base = blockIdx.x * 64 + (wave & 1) * 32;
  const u16* a0 = A + (size_t)(m_base + l16) * 1024 + quad * 8;
  const u16* a1 = a0 + 16 * 1024;
  const u16* b0 = Bt + (size_t)(n_base + l16) * 1024 + quad * 8;
  const u16* b1 = b0 + 16 * 1024;
  f32x4 acc00 = {0.f,0.f,0.f,0.f}, acc01 = acc00, acc10 = acc00, acc11 = acc00;
#pragma unroll 4
  for (int k0 = 0; k0 < 1024; k0 += 32) {
    bf16x8 va0 = *(const bf16x8*)(a0 + k0);
    bf16x8 va1 = *(const bf16x8*)(a1 + k0);
    bf16x8 vb0 = *(const bf16x8*)(b0 + k0);
    bf16x8 vb1 = *(const bf16x8*)(b1 + k0);
    acc00 = MFMA(va0, vb0, acc00);
    acc01 = MFMA(va0, vb1, acc01);
    acc10 = MFMA(va1, vb0, acc10);
    acc11 = MFMA(va1, vb1, acc11);
  }
  f32x4 accs[2][2] = {{acc00, acc01}, {acc10, acc11}};
#pragma unroll
  for (int i = 0; i < 2; ++i)
#pragma unroll
    for (int j = 0; j < 2; ++j) {
      int n = n_base + j * 16 + l16;
      float bv = bias[n];
      int which = n >> 10, e = n & 1023, h = e >> 6, d = e & 63;
#pragma unroll
      for (int r = 0; r < 4; ++r) {
        int m = m_base + i * 16 + quad * 4 + r;
        int b = m >> 11, s = m & 2047;
        float v = accs[i][j][r] + bv;
        size_t off = ((size_t)((b * 16 + h) * 2048 + s)) * 64 + d;
        if (which == 0)      Q[off]  = f2bf(v * QSCALE);  // scale folded into Q
        else if (which == 1) Kp[off] = f2bf(v);
        else                 V[off]  = f2bf(v);
      }
    }
}

// ---- GEMM2: ctx[4096][1024] @ Wp[1024][1024] (+b) -> out fp32 --------------
__global__ __launch_bounds__(256) void k_gemm_proj(const u16* __restrict__ A,
                                                   const u16* __restrict__ Bt,
                                                   const float* __restrict__ bias,
                                                   float* __restrict__ out) {
  int t = threadIdx.x;
  int wave = t >> 6, lane = t & 63, quad = lane >> 4, l16 = lane & 15;
  int m_base = blockIdx.y * 64 + (wave >> 1) * 32;
  int n_base = blockIdx.x * 64 + (wave & 1) * 32;
  const u16* a0 = A + (size_t)(m_base + l16) * 1024 + quad * 8;
  const u16* a1 = a0 + 16 * 1024;
  const u16* b0 = Bt + (size_t)(n_base + l16) * 1024 + quad * 8;
  const u16* b1 = b0 + 16 * 1024;
  f32x4 acc00 = {0.f,0.f,0.f,0.f}, acc01 = acc00, acc10 = acc00, acc11 = acc00;
#pragma unroll 4
  for (int k0 = 0; k0 < 1024; k0 += 32) {
    bf16x8 va0 = *(const bf16x8*)(a0 + k0);
    bf16x8 va1 = *(const bf16x8*)(a1 + k0);
    bf16x8 vb0 = *(const bf16x8*)(b0 + k0);
    bf16x8 vb1 = *(const bf16x8*)(b1 + k0);
    acc00 = MFMA(va0, vb0, acc00);
    acc01 = MFMA(va0, vb1, acc01);
    acc10 = MFMA(va1, vb0, acc10);
    acc11 = MFMA(va1, vb1, acc11);
  }
  f32x4 accs[2][2] = {{acc00, acc01}, {acc10, acc11}};
#pragma unroll
  for (int i = 0; i < 2; ++i)
#pragma unroll
    for (int j = 0; j < 2; ++j) {
      int n = n_base + j * 16 + l16;
      float bv = bias[n];
#pragma unroll
      for (int r = 0; r < 4; ++r) {
        int m = m_base + i * 16 + quad * 4 + r;
        out[(size_t)m * 1024 + n] = accs[i][j][r] + bv;
      }
    }
}

// ---- fused causal attention ------------------------------------------------
// One wave per 16 q-rows. Pass1: per-lane online softmax over QK^T tiles
// (no cross-lane in loop; -1e30 sentinel keeps math NaN-free), then width-16
// butterfly merge -> exact row m, l. Pass2: recompute scores, write normalized
// weights (full row incl. zero-fill), P via LDS round-trip -> PV MFMA.
__global__ __launch_bounds__(256) void k_attn(const u16* __restrict__ Q,
                                              const u16* __restrict__ Kp,
                                              const u16* __restrict__ Vt,
                                              u16* __restrict__ ctx,
                                              float* __restrict__ Wout) {
  __shared__ u16 Pb[4][16][40];                       // per-wave P staging (+pad)
  int t = threadIdx.x;
  int w = t >> 6, lane = t & 63, quad = lane >> 4, l16 = lane & 15;
  int bh = blockIdx.y;
  int q0 = blockIdx.x * 64 + w * 16;

  const u16* qrow = Q + ((size_t)bh * 2048 + q0 + l16) * 64 + quad * 8;
  bf16x8 aq0 = *(const bf16x8*)(qrow);                // A-frag, d 0..31
  bf16x8 aq1 = *(const bf16x8*)(qrow + 32);           // A-frag, d 32..63

  const u16* kbase = Kp + (size_t)bh * 2048 * 64;
  float m[4] = {-1e30f, -1e30f, -1e30f, -1e30f};
  float l[4] = {0.f, 0.f, 0.f, 0.f};
  int qmax = q0 + 15;
  int nt1 = q0 / 16 + 1;                              // tiles covering cols [0, q0+16)

  for (int kt = 0; kt < nt1; ++kt) {
    const u16* kr = kbase + (size_t)(kt * 16 + l16) * 64 + quad * 8;
    bf16x8 b0 = *(const bf16x8*)(kr);
    bf16x8 b1 = *(const bf16x8*)(kr + 32);
    f32x4 c = {0.f, 0.f, 0.f, 0.f};
    c = MFMA(aq0, b0, c);
    c = MFMA(aq1, b1, c);
    int col = kt * 16 + l16;
#pragma unroll
    for (int r = 0; r < 4; ++r) {
      int q = q0 + quad * 4 + r;
      float v = (col <= q) ? c[r] : -1e30f;
      float nm = fmaxf(m[r], v);
      l[r] = l[r] * E2(m[r] - nm) + E2(v - nm);
      m[r] = nm;
    }
  }
  // merge 16 lanes of each quad-group (rows q0+quad*4+r)
#pragma unroll
  for (int r = 0; r < 4; ++r) {
#pragma unroll
    for (int off = 1; off < 16; off <<= 1) {
      float om = __shfl_xor(m[r], off, 16);
      float ol = __shfl_xor(l[r], off, 16);
      float nm = fmaxf(m[r], om);
      l[r] = l[r] * E2(m[r] - nm) + ol * E2(om - nm);
      m[r] = nm;
    }
  }
  float rl[4];
#pragma unroll
  for (int r = 0; r < 4; ++r) rl[r] = 1.f / l[r];     // l >= 1 (diag always valid)

  // pass 2
  f32x4 o0 = {0.f,0.f,0.f,0.f}, o1 = o0, o2 = o0, o3 = o0;
  f32x4 oacc[4] = {o0, o1, o2, o3};
  u16* pw = &Pb[w][0][0];
  const u16* vtb = Vt + (size_t)bh * 64 * 2048;
  float* wrow = Wout + (size_t)bh * 2048 * 2048;

  for (int kt2 = 0; kt2 < 64; ++kt2) {
    int k0 = kt2 * 32;
    bool active = (k0 <= qmax);
    f32x4 cc[2] = {{0.f,0.f,0.f,0.f}, {0.f,0.f,0.f,0.f}};
    if (active) {
      const u16* kr = kbase + (size_t)(k0 + l16) * 64 + quad * 8;
      bf16x8 b00 = *(const bf16x8*)(kr);
      bf16x8 b01 = *(const bf16x8*)(kr + 32);
      const u16* kr2 = kr + 16 * 64;
      bf16x8 b10 = *(const bf16x8*)(kr2);
      bf16x8 b11 = *(const bf16x8*)(kr2 + 32);
      cc[0] = MFMA(aq0, b00, cc[0]);
      cc[0] = MFMA(aq1, b01, cc[0]);
      cc[1] = MFMA(aq0, b10, cc[1]);
      cc[1] = MFMA(aq1, b11, cc[1]);
    }
#pragma unroll
    for (int sub = 0; sub < 2; ++sub) {
      int col = k0 + sub * 16 + l16;
#pragma unroll
      for (int r = 0; r < 4; ++r) {
        int q = q0 + quad * 4 + r;
        float p = (active && col <= q) ? E2(cc[sub][r] - m[r]) * rl[r] : 0.f;
        wrow[(size_t)q * 2048 + col] = p;             // normalized weight (or 0)
        pw[(quad * 4 + r) * 40 + sub * 16 + l16] = f2bf(p);
      }
    }
    if (active) {
      // C-layout -> A-layout via LDS (same-wave DS ordering is in-order)
      bf16x8 pa = *(const bf16x8*)(pw + l16 * 40 + quad * 8);
#pragma unroll
      for (int s4 = 0; s4 < 4; ++s4) {
        const u16* vr = vtb + (size_t)(s4 * 16 + l16) * 2048 + k0 + quad * 8;
        bf16x8 bv = *(const bf16x8*)(vr);
        oacc[s4] = MFMA(pa, bv, oacc[s4]);
      }
    }
  }
  // ctx[b][s][h*64+d]
  int b = bh >> 4, h = bh & 15;
#pragma unroll
  for (int s4 = 0; s4 < 4; ++s4)
#pragma unroll
    for (int r = 0; r < 4; ++r) {
      int q = q0 + quad * 4 + r;
      int d = s4 * 16 + l16;
      ctx[((size_t)(b * 2048 + q)) * 1024 + h * 64 + d] = f2bf(oacc[s4][r]);
    }
}

// ---------------------------------------------------------------------------
extern "C" void kernel_launch(void* const* d_in, const int* in_sizes, int n_in,
                              void* d_out, int out_size, void* d_ws, size_t ws_size,
                              hipStream_t stream) {
  const float* hs     = (const float*)d_in[0];
  const float* w_attn = (const float*)d_in[1];
  const float* b_attn = (const float*)d_in[2];
  const float* w_proj = (const float*)d_in[3];
  const float* b_proj = (const float*)d_in[4];

  char*  outc  = (char*)d_out;
  float* out_f = (float*)d_out;
  float* Wout  = out_f + 4194304;                 // weights region (512 MB)

  // scratch carved out of d_out (dead/alive windows don't overlap):
  u16* qbuf = (u16*)outc;                         // attn_out region: Q (8 MB)
  u16* kbuf = (u16*)(outc + 8388608);             //                  K (8 MB)
  u16* hsb  = (u16*)(outc + 530579456);           // weights tail: hs bf16 (8 MB)
  u16* wtA  = (u16*)(outc + 538968064);           //               w_attn^T (6 MB)
  u16* vbuf = (u16*)(outc + 545259520);           //               V (8 MB)

  char* ws  = (char*)d_ws;                        // 18 MB of d_ws used
  u16*  vt  = (u16*)ws;                           // V^T (8 MB)
  u16*  ctx = (u16*)(ws + 8388608);               // pre-proj context (8 MB)
  u16*  wtP = (u16*)(ws + 16777216);              // w_proj^T (2 MB)

  k_cast<<<4096, 256, 0, stream>>>(hs, hsb, 4194304);
  k_transpose_cast<<<dim3(48, 16), 256, 0, stream>>>(w_attn, wtA, 1024, 3072);
  k_transpose_cast<<<dim3(16, 16), 256, 0, stream>>>(w_proj, wtP, 1024, 1024);
  k_gemm_qkv<<<dim3(48, 64), 256, 0, stream>>>(hsb, wtA, b_attn, qbuf, kbuf, vbuf);
  k_transpose_v<<<dim3(32, 32), 256, 0, stream>>>(vbuf, vt);
  k_attn<<<dim3(32, 32), 256, 0, stream>>>(qbuf, kbuf, vt, ctx, Wout);
  k_gemm_proj<<<dim3(16, 64), 256, 0, stream>>>(ctx, wtP, b_proj, out_f);
}

// Round 2
// 902.625 us; speedup vs baseline: 1.1864x; 1.1864x over previous
//
#include <hip/hip_runtime.h>

// ---------------------------------------------------------------------------
// TfmrAttention: B=2, S=2048, E=1024, H=16, D=64
// out = [attn_out (4,194,304 f32) | attn_weights (134,217,728 f32)]
// R2: coalesced float4 weight stores via LDS staging + fast zero-fill +
//     heavy-first block order; m97-style 128x128 LDS GEMMs w/ global_load_lds.
// ---------------------------------------------------------------------------

typedef unsigned short u16;
typedef __attribute__((ext_vector_type(8))) short bf16x8;   // 8 bf16 = 4 VGPRs
typedef __attribute__((ext_vector_type(4))) float f32x4;
typedef __attribute__((ext_vector_type(4))) unsigned short u16x4;

#define MFMA(a, b, c) __builtin_amdgcn_mfma_f32_16x16x32_bf16((a), (b), (c), 0, 0, 0)

typedef const __attribute__((address_space(1))) void* gas_t;
typedef __attribute__((address_space(3))) void* las_t;
__device__ __forceinline__ void async_copy16(const void* g, void* l) {
  // wave-uniform LDS base + lane*16 (m104/m108 constraint respected by callers)
  __builtin_amdgcn_global_load_lds((gas_t)g, (las_t)l, 16, 0, 0);
}

__device__ __forceinline__ u16 f2bf(float f) {          // RNE fp32->bf16
  unsigned u = __builtin_bit_cast(unsigned, f);
  u += 0x7FFFu + ((u >> 16) & 1u);
  return (u16)(u >> 16);
}
__device__ __forceinline__ float E2(float x) { return __builtin_amdgcn_exp2f(x); }

// 0.125 * log2(e): fold 1/sqrt(64) and natural->base2 exp into Q
#define QSCALE 0.18033688011112042f

// ---- cast fp32 -> bf16, 4 elems/thread ------------------------------------
__global__ __launch_bounds__(256) void k_cast(const float* __restrict__ in,
                                              u16* __restrict__ out, int n) {
  int i = (blockIdx.x * 256 + threadIdx.x) * 4;
  if (i + 3 < n) {
    float4 v = *(const float4*)(in + i);
    u16x4 o = { f2bf(v.x), f2bf(v.y), f2bf(v.z), f2bf(v.w) };
    *(u16x4*)(out + i) = o;
  }
}

// ---- transpose + cast: W[Kd][Nd] fp32 -> Wt[Nd][Kd] bf16 -------------------
__global__ __launch_bounds__(256) void k_transpose_cast(const float* __restrict__ in,
                                                        u16* __restrict__ out,
                                                        int Kd, int Nd) {
  __shared__ float tile[64][65];
  int n0 = blockIdx.x * 64, k0 = blockIdx.y * 64;
  int t = threadIdx.x, col = t & 63, r4 = t >> 6;
#pragma unroll
  for (int ph = 0; ph < 16; ++ph) {
    int row = ph * 4 + r4;
    tile[row][col] = in[(size_t)(k0 + row) * Nd + n0 + col];
  }
  __syncthreads();
#pragma unroll
  for (int ph = 0; ph < 16; ++ph) {
    int row = ph * 4 + r4;
    out[(size_t)(n0 + row) * Kd + k0 + col] = f2bf(tile[col][row]);
  }
}

// ---- transpose bf16: V[bh][2048][64] -> Vt[bh][64][2048] -------------------
__global__ __launch_bounds__(256) void k_transpose_v(const u16* __restrict__ V,
                                                     u16* __restrict__ Vt) {
  __shared__ u16 tile[64][65];
  int bh = blockIdx.y, s0 = blockIdx.x * 64;
  int t = threadIdx.x, col = t & 63, r4 = t >> 6;
#pragma unroll
  for (int ph = 0; ph < 16; ++ph) {
    int row = ph * 4 + r4;
    tile[row][col] = V[((size_t)bh * 2048 + s0 + row) * 64 + col];
  }
  __syncthreads();
#pragma unroll
  for (int ph = 0; ph < 16; ++ph) {
    int row = ph * 4 + r4;
    Vt[((size_t)bh * 64 + row) * 2048 + s0 + col] = tile[col][row];
  }
}

// ---- m97-style GEMM core macro: 128x128 tile, BK=32, global_load_lds -------
// A[M][1024], Bt[N][1024] bf16. 4 waves in 2x2, each wave 64x64 (4x4 accs).
#define GEMM_PROLOG()                                                          \
  __shared__ u16 As[128 * 32];                                                 \
  __shared__ u16 Bs[128 * 32];                                                 \
  int t = threadIdx.x;                                                         \
  int wave = t >> 6, lane = t & 63, quad = lane >> 4, l16 = lane & 15;         \
  int wm = wave >> 1, wn = wave & 1;                                           \
  int m0 = blockIdx.y * 128, n0 = blockIdx.x * 128;                            \
  /* staging map: flat16 f = wave*64+lane (+256); row=f>>2, col8=(f&3)*8 */    \
  int f1 = wave * 64 + lane, f2 = f1 + 256;                                    \
  const u16* gA1 = A + (size_t)(m0 + (f1 >> 2)) * 1024 + (f1 & 3) * 8;         \
  const u16* gA2 = A + (size_t)(m0 + (f2 >> 2)) * 1024 + (f2 & 3) * 8;         \
  const u16* gB1 = Bt + (size_t)(n0 + (f1 >> 2)) * 1024 + (f1 & 3) * 8;        \
  const u16* gB2 = Bt + (size_t)(n0 + (f2 >> 2)) * 1024 + (f2 & 3) * 8;        \
  u16* lA1 = As + wave * 512;        /* wave-uniform bases (elements) */       \
  u16* lA2 = As + 2048 + wave * 512;                                           \
  u16* lB1 = Bs + wave * 512;                                                  \
  u16* lB2 = Bs + 2048 + wave * 512;                                           \
  f32x4 acc[4][4];                                                             \
  for (int i = 0; i < 4; ++i)                                                  \
    for (int j = 0; j < 4; ++j) acc[i][j] = (f32x4){0.f, 0.f, 0.f, 0.f};       \
  for (int k0 = 0; k0 < 1024; k0 += 32) {                                      \
    async_copy16(gA1 + k0, lA1);                                               \
    async_copy16(gA2 + k0, lA2);                                               \
    async_copy16(gB1 + k0, lB1);                                               \
    async_copy16(gB2 + k0, lB2);                                               \
    __syncthreads();                                                           \
    bf16x8 fa[4], fb[4];                                                       \
    _Pragma("unroll") for (int i = 0; i < 4; ++i)                              \
        fa[i] = *(const bf16x8*)(As + (wm * 64 + i * 16 + l16) * 32 + quad * 8);\
    _Pragma("unroll") for (int j = 0; j < 4; ++j)                              \
        fb[j] = *(const bf16x8*)(Bs + (wn * 64 + j * 16 + l16) * 32 + quad * 8);\
    _Pragma("unroll") for (int i = 0; i < 4; ++i)                              \
      _Pragma("unroll") for (int j = 0; j < 4; ++j)                            \
          acc[i][j] = MFMA(fa[i], fb[j], acc[i][j]);                           \
    __syncthreads();                                                           \
  }

// GEMM1: hs[4096][1024] @ W[1024][3072] (+b) -> Q,K,V bf16 [b,h,s,d]
__global__ __launch_bounds__(256) void k_gemm_qkv(const u16* __restrict__ A,
                                                  const u16* __restrict__ Bt,
                                                  const float* __restrict__ bias,
                                                  u16* __restrict__ Q,
                                                  u16* __restrict__ Kp,
                                                  u16* __restrict__ V) {
  GEMM_PROLOG()
#pragma unroll
  for (int j = 0; j < 4; ++j) {
    int n = n0 + wn * 64 + j * 16 + l16;
    float bv = bias[n];
    int which = n >> 10, e = n & 1023, h = e >> 6, d = e & 63;
#pragma unroll
    for (int i = 0; i < 4; ++i)
#pragma unroll
      for (int r = 0; r < 4; ++r) {
        int m = m0 + wm * 64 + i * 16 + quad * 4 + r;
        int b = m >> 11, s = m & 2047;
        float v = acc[i][j][r] + bv;
        size_t off = ((size_t)((b * 16 + h) * 2048 + s)) * 64 + d;
        if (which == 0)      Q[off]  = f2bf(v * QSCALE);
        else if (which == 1) Kp[off] = f2bf(v);
        else                 V[off]  = f2bf(v);
      }
  }
}

// GEMM2: ctx[4096][1024] @ Wp[1024][1024] (+b) -> out fp32
__global__ __launch_bounds__(256) void k_gemm_proj(const u16* __restrict__ A,
                                                   const u16* __restrict__ Bt,
                                                   const float* __restrict__ bias,
                                                   float* __restrict__ out) {
  GEMM_PROLOG()
#pragma unroll
  for (int j = 0; j < 4; ++j) {
    int n = n0 + wn * 64 + j * 16 + l16;
    float bv = bias[n];
#pragma unroll
    for (int i = 0; i < 4; ++i)
#pragma unroll
      for (int r = 0; r < 4; ++r) {
        int m = m0 + wm * 64 + i * 16 + quad * 4 + r;
        out[(size_t)m * 1024 + n] = acc[i][j][r] + bv;
      }
  }
}

// ---- fused causal attention ------------------------------------------------
// One wave per 16 q-rows. Pass1: per-lane online softmax, width-16 merge.
// Pass2: recompute scores; P staged in LDS fp32 (stride 36) -> float4
// coalesced weight stores; bf16 P -> PV MFMA. Upper triangle zero-filled in a
// dedicated float4 loop. Heavy q-tiles dispatch first (reversed blockIdx.x).
__global__ __launch_bounds__(256) void k_attn(const u16* __restrict__ Q,
                                              const u16* __restrict__ Kp,
                                              const u16* __restrict__ Vt,
                                              u16* __restrict__ ctx,
                                              float* __restrict__ Wout) {
  __shared__ float Pf[4][16 * 36];                    // fp32 store staging
  __shared__ u16 Pb[4][16][40];                       // bf16 PV staging
  int t = threadIdx.x;
  int w = t >> 6, lane = t & 63, quad = lane >> 4, l16 = lane & 15;
  int bh = blockIdx.y;
  int q0 = (gridDim.x - 1 - blockIdx.x) * 64 + w * 16;   // heavy tiles first

  const u16* qrow = Q + ((size_t)bh * 2048 + q0 + l16) * 64 + quad * 8;
  bf16x8 aq0 = *(const bf16x8*)(qrow);
  bf16x8 aq1 = *(const bf16x8*)(qrow + 32);

  const u16* kbase = Kp + (size_t)bh * 2048 * 64;
  float m[4] = {-1e30f, -1e30f, -1e30f, -1e30f};
  float l[4] = {0.f, 0.f, 0.f, 0.f};
  int qmax = q0 + 15;
  int nt1 = q0 / 16 + 1;

  for (int kt = 0; kt < nt1; ++kt) {
    const u16* kr = kbase + (size_t)(kt * 16 + l16) * 64 + quad * 8;
    bf16x8 b0 = *(const bf16x8*)(kr);
    bf16x8 b1 = *(const bf16x8*)(kr + 32);
    f32x4 c = {0.f, 0.f, 0.f, 0.f};
    c = MFMA(aq0, b0, c);
    c = MFMA(aq1, b1, c);
    int col = kt * 16 + l16;
#pragma unroll
    for (int r = 0; r < 4; ++r) {
      int q = q0 + quad * 4 + r;
      float v = (col <= q) ? c[r] : -1e30f;
      float nm = fmaxf(m[r], v);
      l[r] = l[r] * E2(m[r] - nm) + E2(v - nm);
      m[r] = nm;
    }
  }
#pragma unroll
  for (int r = 0; r < 4; ++r) {
#pragma unroll
    for (int off = 1; off < 16; off <<= 1) {
      float om = __shfl_xor(m[r], off, 16);
      float ol = __shfl_xor(l[r], off, 16);
      float nm = fmaxf(m[r], om);
      l[r] = l[r] * E2(m[r] - nm) + ol * E2(om - nm);
      m[r] = nm;
    }
  }
  float rl[4];
#pragma unroll
  for (int r = 0; r < 4; ++r) rl[r] = 1.f / l[r];

  // pass 2 — active tiles only
  f32x4 oacc[4];
#pragma unroll
  for (int s4 = 0; s4 < 4; ++s4) oacc[s4] = (f32x4){0.f, 0.f, 0.f, 0.f};
  u16* pw = &Pb[w][0][0];
  float* pf = &Pf[w][0];
  const u16* vtb = Vt + (size_t)bh * 64 * 2048;
  float* wrow = Wout + (size_t)bh * 2048 * 2048;
  int srow = lane >> 3, scol = (lane & 7) << 2;       // coalesced store map

  int na = qmax / 32 + 1;                             // active 32-col tiles
  for (int kt2 = 0; kt2 < na; ++kt2) {
    int k0 = kt2 * 32;
    f32x4 cc[2] = {{0.f,0.f,0.f,0.f}, {0.f,0.f,0.f,0.f}};
    const u16* kr = kbase + (size_t)(k0 + l16) * 64 + quad * 8;
    bf16x8 b00 = *(const bf16x8*)(kr);
    bf16x8 b01 = *(const bf16x8*)(kr + 32);
    const u16* kr2 = kr + 16 * 64;
    bf16x8 b10 = *(const bf16x8*)(kr2);
    bf16x8 b11 = *(const bf16x8*)(kr2 + 32);
    cc[0] = MFMA(aq0, b00, cc[0]);
    cc[0] = MFMA(aq1, b01, cc[0]);
    cc[1] = MFMA(aq0, b10, cc[1]);
    cc[1] = MFMA(aq1, b11, cc[1]);
#pragma unroll
    for (int sub = 0; sub < 2; ++sub) {
      int col = k0 + sub * 16 + l16;
#pragma unroll
      for (int r = 0; r < 4; ++r) {
        int q = q0 + quad * 4 + r;
        float p = (col <= q) ? E2(cc[sub][r] - m[r]) * rl[r] : 0.f;
        pf[(quad * 4 + r) * 36 + sub * 16 + l16] = p;
        pw[(quad * 4 + r) * 40 + sub * 16 + l16] = f2bf(p);
      }
    }
    // coalesced fp32 store: 2 float4/lane, 8 rows x 128B contiguous per instr
    f32x4 v0 = *(const f32x4*)(pf + srow * 36 + scol);
    f32x4 v1 = *(const f32x4*)(pf + (srow + 8) * 36 + scol);
    *(f32x4*)(wrow + (size_t)(q0 + srow) * 2048 + k0 + scol) = v0;
    *(f32x4*)(wrow + (size_t)(q0 + srow + 8) * 2048 + k0 + scol) = v1;
    // PV
    bf16x8 pa = *(const bf16x8*)(pw + l16 * 40 + quad * 8);
#pragma unroll
    for (int s4 = 0; s4 < 4; ++s4) {
      const u16* vr = vtb + (size_t)(s4 * 16 + l16) * 2048 + k0 + quad * 8;
      bf16x8 bv = *(const bf16x8*)(vr);
      oacc[s4] = MFMA(pa, bv, oacc[s4]);
    }
  }
  // zero-fill the masked remainder [na*32, 2048) — 1KB per instruction
  int zstart = na * 32;
  f32x4 z = {0.f, 0.f, 0.f, 0.f};
  for (int r = 0; r < 16; ++r) {
    float* rb = wrow + (size_t)(q0 + r) * 2048;
    for (int c = zstart + (lane << 2); c < 2048; c += 256)
      *(f32x4*)(rb + c) = z;
  }
  // ctx[b][s][h*64+d]
  int b = bh >> 4, h = bh & 15;
#pragma unroll
  for (int s4 = 0; s4 < 4; ++s4)
#pragma unroll
    for (int r = 0; r < 4; ++r) {
      int q = q0 + quad * 4 + r;
      int d = s4 * 16 + l16;
      ctx[((size_t)(b * 2048 + q)) * 1024 + h * 64 + d] = f2bf(oacc[s4][r]);
    }
}

// ---------------------------------------------------------------------------
extern "C" void kernel_launch(void* const* d_in, const int* in_sizes, int n_in,
                              void* d_out, int out_size, void* d_ws, size_t ws_size,
                              hipStream_t stream) {
  const float* hs     = (const float*)d_in[0];
  const float* w_attn = (const float*)d_in[1];
  const float* b_attn = (const float*)d_in[2];
  const float* w_proj = (const float*)d_in[3];
  const float* b_proj = (const float*)d_in[4];

  char*  outc  = (char*)d_out;
  float* out_f = (float*)d_out;
  float* Wout  = out_f + 4194304;                 // weights region (512 MB)

  // scratch carved out of d_out (dead/alive windows don't overlap):
  u16* qbuf = (u16*)outc;                         // attn_out region: Q (8 MB)
  u16* kbuf = (u16*)(outc + 8388608);             //                  K (8 MB)
  u16* hsb  = (u16*)(outc + 530579456);           // weights tail: hs bf16 (8 MB)
  u16* wtA  = (u16*)(outc + 538968064);           //               w_attn^T (6 MB)
  u16* vbuf = (u16*)(outc + 545259520);           //               V (8 MB)

  char* ws  = (char*)d_ws;                        // 18 MB of d_ws used
  u16*  vt  = (u16*)ws;                           // V^T (8 MB)
  u16*  ctx = (u16*)(ws + 8388608);               // pre-proj context (8 MB)
  u16*  wtP = (u16*)(ws + 16777216);              // w_proj^T (2 MB)

  k_cast<<<4096, 256, 0, stream>>>(hs, hsb, 4194304);
  k_transpose_cast<<<dim3(48, 16), 256, 0, stream>>>(w_attn, wtA, 1024, 3072);
  k_transpose_cast<<<dim3(16, 16), 256, 0, stream>>>(w_proj, wtP, 1024, 1024);
  k_gemm_qkv<<<dim3(24, 32), 256, 0, stream>>>(hsb, wtA, b_attn, qbuf, kbuf, vbuf);
  k_transpose_v<<<dim3(32, 32), 256, 0, stream>>>(vbuf, vt);
  k_attn<<<dim3(32, 32), 256, 0, stream>>>(qbuf, kbuf, vt, ctx, Wout);
  k_gemm_proj<<<dim3(8, 32), 256, 0, stream>>>(ctx, wtP, b_proj, out_f);
}

// Round 3
// 790.515 us; speedup vs baseline: 1.3547x; 1.1418x over previous
//
#include <hip/hip_runtime.h>

// ---------------------------------------------------------------------------
// TfmrAttention: B=2, S=2048, E=1024, H=16, D=64
// out = [attn_out (4,194,304 f32) | attn_weights (134,217,728 f32)]
// R3: k_attn load-balance fix — co-resident blocks (ids ≡ mod 256) now carry
//     constant total causal work; pass-1 dual-chain ILP + K prefetch;
//     pass-2 fp32-only LDS staging.
// ---------------------------------------------------------------------------

typedef unsigned short u16;
typedef __attribute__((ext_vector_type(8))) short bf16x8;   // 8 bf16 = 4 VGPRs
typedef __attribute__((ext_vector_type(4))) float f32x4;
typedef __attribute__((ext_vector_type(4))) unsigned short u16x4;

#define MFMA(a, b, c) __builtin_amdgcn_mfma_f32_16x16x32_bf16((a), (b), (c), 0, 0, 0)

typedef const __attribute__((address_space(1))) void* gas_t;
typedef __attribute__((address_space(3))) void* las_t;
__device__ __forceinline__ void async_copy16(const void* g, void* l) {
  __builtin_amdgcn_global_load_lds((gas_t)g, (las_t)l, 16, 0, 0);
}

__device__ __forceinline__ u16 f2bf(float f) {          // RNE fp32->bf16
  unsigned u = __builtin_bit_cast(unsigned, f);
  u += 0x7FFFu + ((u >> 16) & 1u);
  return (u16)(u >> 16);
}
__device__ __forceinline__ float E2(float x) { return __builtin_amdgcn_exp2f(x); }

// 0.125 * log2(e): fold 1/sqrt(64) and natural->base2 exp into Q
#define QSCALE 0.18033688011112042f

// ---- cast fp32 -> bf16, 4 elems/thread ------------------------------------
__global__ __launch_bounds__(256) void k_cast(const float* __restrict__ in,
                                              u16* __restrict__ out, int n) {
  int i = (blockIdx.x * 256 + threadIdx.x) * 4;
  if (i + 3 < n) {
    float4 v = *(const float4*)(in + i);
    u16x4 o = { f2bf(v.x), f2bf(v.y), f2bf(v.z), f2bf(v.w) };
    *(u16x4*)(out + i) = o;
  }
}

// ---- transpose + cast: W[Kd][Nd] fp32 -> Wt[Nd][Kd] bf16 -------------------
__global__ __launch_bounds__(256) void k_transpose_cast(const float* __restrict__ in,
                                                        u16* __restrict__ out,
                                                        int Kd, int Nd) {
  __shared__ float tile[64][65];
  int n0 = blockIdx.x * 64, k0 = blockIdx.y * 64;
  int t = threadIdx.x, col = t & 63, r4 = t >> 6;
#pragma unroll
  for (int ph = 0; ph < 16; ++ph) {
    int row = ph * 4 + r4;
    tile[row][col] = in[(size_t)(k0 + row) * Nd + n0 + col];
  }
  __syncthreads();
#pragma unroll
  for (int ph = 0; ph < 16; ++ph) {
    int row = ph * 4 + r4;
    out[(size_t)(n0 + row) * Kd + k0 + col] = f2bf(tile[col][row]);
  }
}

// ---- transpose bf16: V[bh][2048][64] -> Vt[bh][64][2048] -------------------
__global__ __launch_bounds__(256) void k_transpose_v(const u16* __restrict__ V,
                                                     u16* __restrict__ Vt) {
  __shared__ u16 tile[64][65];
  int bh = blockIdx.y, s0 = blockIdx.x * 64;
  int t = threadIdx.x, col = t & 63, r4 = t >> 6;
#pragma unroll
  for (int ph = 0; ph < 16; ++ph) {
    int row = ph * 4 + r4;
    tile[row][col] = V[((size_t)bh * 2048 + s0 + row) * 64 + col];
  }
  __syncthreads();
#pragma unroll
  for (int ph = 0; ph < 16; ++ph) {
    int row = ph * 4 + r4;
    Vt[((size_t)bh * 64 + row) * 2048 + s0 + col] = tile[col][row];
  }
}

// ---- m97-style GEMM core macro: 128x128 tile, BK=32, global_load_lds -------
#define GEMM_PROLOG()                                                          \
  __shared__ u16 As[128 * 32];                                                 \
  __shared__ u16 Bs[128 * 32];                                                 \
  int t = threadIdx.x;                                                         \
  int wave = t >> 6, lane = t & 63, quad = lane >> 4, l16 = lane & 15;         \
  int wm = wave >> 1, wn = wave & 1;                                           \
  int m0 = blockIdx.y * 128, n0 = blockIdx.x * 128;                            \
  int f1 = wave * 64 + lane, f2 = f1 + 256;                                    \
  const u16* gA1 = A + (size_t)(m0 + (f1 >> 2)) * 1024 + (f1 & 3) * 8;         \
  const u16* gA2 = A + (size_t)(m0 + (f2 >> 2)) * 1024 + (f2 & 3) * 8;         \
  const u16* gB1 = Bt + (size_t)(n0 + (f1 >> 2)) * 1024 + (f1 & 3) * 8;        \
  const u16* gB2 = Bt + (size_t)(n0 + (f2 >> 2)) * 1024 + (f2 & 3) * 8;        \
  u16* lA1 = As + wave * 512;                                                  \
  u16* lA2 = As + 2048 + wave * 512;                                           \
  u16* lB1 = Bs + wave * 512;                                                  \
  u16* lB2 = Bs + 2048 + wave * 512;                                           \
  f32x4 acc[4][4];                                                             \
  for (int i = 0; i < 4; ++i)                                                  \
    for (int j = 0; j < 4; ++j) acc[i][j] = (f32x4){0.f, 0.f, 0.f, 0.f};       \
  for (int k0 = 0; k0 < 1024; k0 += 32) {                                      \
    async_copy16(gA1 + k0, lA1);                                               \
    async_copy16(gA2 + k0, lA2);                                               \
    async_copy16(gB1 + k0, lB1);                                               \
    async_copy16(gB2 + k0, lB2);                                               \
    __syncthreads();                                                           \
    bf16x8 fa[4], fb[4];                                                       \
    _Pragma("unroll") for (int i = 0; i < 4; ++i)                              \
        fa[i] = *(const bf16x8*)(As + (wm * 64 + i * 16 + l16) * 32 + quad * 8);\
    _Pragma("unroll") for (int j = 0; j < 4; ++j)                              \
        fb[j] = *(const bf16x8*)(Bs + (wn * 64 + j * 16 + l16) * 32 + quad * 8);\
    _Pragma("unroll") for (int i = 0; i < 4; ++i)                              \
      _Pragma("unroll") for (int j = 0; j < 4; ++j)                            \
          acc[i][j] = MFMA(fa[i], fb[j], acc[i][j]);                           \
    __syncthreads();                                                           \
  }

// GEMM1: hs[4096][1024] @ W[1024][3072] (+b) -> Q,K,V bf16 [b,h,s,d]
__global__ __launch_bounds__(256) void k_gemm_qkv(const u16* __restrict__ A,
                                                  const u16* __restrict__ Bt,
                                                  const float* __restrict__ bias,
                                                  u16* __restrict__ Q,
                                                  u16* __restrict__ Kp,
                                                  u16* __restrict__ V) {
  GEMM_PROLOG()
#pragma unroll
  for (int j = 0; j < 4; ++j) {
    int n = n0 + wn * 64 + j * 16 + l16;
    float bv = bias[n];
    int which = n >> 10, e = n & 1023, h = e >> 6, d = e & 63;
#pragma unroll
    for (int i = 0; i < 4; ++i)
#pragma unroll
      for (int r = 0; r < 4; ++r) {
        int m = m0 + wm * 64 + i * 16 + quad * 4 + r;
        int b = m >> 11, s = m & 2047;
        float v = acc[i][j][r] + bv;
        size_t off = ((size_t)((b * 16 + h) * 2048 + s)) * 64 + d;
        if (which == 0)      Q[off]  = f2bf(v * QSCALE);
        else if (which == 1) Kp[off] = f2bf(v);
        else                 V[off]  = f2bf(v);
      }
  }
}

// GEMM2: ctx[4096][1024] @ Wp[1024][1024] (+b) -> out fp32
__global__ __launch_bounds__(256) void k_gemm_proj(const u16* __restrict__ A,
                                                   const u16* __restrict__ Bt,
                                                   const float* __restrict__ bias,
                                                   float* __restrict__ out) {
  GEMM_PROLOG()
#pragma unroll
  for (int j = 0; j < 4; ++j) {
    int n = n0 + wn * 64 + j * 16 + l16;
    float bv = bias[n];
#pragma unroll
    for (int i = 0; i < 4; ++i)
#pragma unroll
      for (int r = 0; r < 4; ++r) {
        int m = m0 + wm * 64 + i * 16 + quad * 4 + r;
        out[(size_t)m * 1024 + n] = acc[i][j][r] + bv;
      }
  }
}

// ---- fused causal attention ------------------------------------------------
// Grid: 1024 1-D blocks. bh = id&31, i = id>>5 -> (j = i&7, s = i>>3);
// q-tile qt = {j, 15-j, 16+j, 31-j}[s]. Co-resident blocks on a CU are ids
// ≡ c (mod 256) => same j, all four s => Σqt = 62 = constant per-CU work.
__global__ __launch_bounds__(256, 4) void k_attn(const u16* __restrict__ Q,
                                                 const u16* __restrict__ Kp,
                                                 const u16* __restrict__ Vt,
                                                 u16* __restrict__ ctx,
                                                 float* __restrict__ Wout) {
  __shared__ float Pf[4][16 * 36];                    // fp32 P staging (+pad)
  int t = threadIdx.x;
  int w = t >> 6, lane = t & 63, quad = lane >> 4, l16 = lane & 15;
  int id = blockIdx.x;
  int bh = id & 31;
  int ii = id >> 5, jj = ii & 7, ss = ii >> 3;
  int qt = (ss == 0) ? jj : (ss == 1) ? 15 - jj : (ss == 2) ? 16 + jj : 31 - jj;
  int q0 = qt * 64 + w * 16;

  const u16* qrow = Q + ((size_t)bh * 2048 + q0 + l16) * 64 + quad * 8;
  bf16x8 aq0 = *(const bf16x8*)(qrow);
  bf16x8 aq1 = *(const bf16x8*)(qrow + 32);

  const u16* kbase = Kp + (size_t)bh * 2048 * 64;
  int qmax = q0 + 15;

  // ---- pass 1: dual-chain online softmax over 32-col tiles, K prefetch ----
  float m0[4], l0[4], m1[4], l1[4];
#pragma unroll
  for (int r = 0; r < 4; ++r) { m0[r] = m1[r] = -1e30f; l0[r] = l1[r] = 0.f; }
  int nt = (q0 + 47) >> 5;                            // 32-col tiles over [0, q0+16)

  const u16* kr0 = kbase + (size_t)l16 * 64 + quad * 8;
  bf16x8 nb00 = *(const bf16x8*)(kr0);
  bf16x8 nb01 = *(const bf16x8*)(kr0 + 32);
  bf16x8 nb10 = *(const bf16x8*)(kr0 + 1024);
  bf16x8 nb11 = *(const bf16x8*)(kr0 + 1024 + 32);
  for (int kt = 0; kt < nt; ++kt) {
    bf16x8 b00 = nb00, b01 = nb01, b10 = nb10, b11 = nb11;
    if (kt + 1 < nt) {
      const u16* kn = kbase + (size_t)((kt + 1) * 32 + l16) * 64 + quad * 8;
      nb00 = *(const bf16x8*)(kn);
      nb01 = *(const bf16x8*)(kn + 32);
      nb10 = *(const bf16x8*)(kn + 1024);
      nb11 = *(const bf16x8*)(kn + 1024 + 32);
    }
    f32x4 c0 = {0.f, 0.f, 0.f, 0.f}, c1 = c0;
    c0 = MFMA(aq0, b00, c0);
    c0 = MFMA(aq1, b01, c0);
    c1 = MFMA(aq0, b10, c1);
    c1 = MFMA(aq1, b11, c1);
    int col0 = kt * 32 + l16, col1 = col0 + 16;
#pragma unroll
    for (int r = 0; r < 4; ++r) {
      int q = q0 + quad * 4 + r;
      float v0 = (col0 <= q) ? c0[r] : -1e30f;        // chain 0
      float nm0 = fmaxf(m0[r], v0);
      l0[r] = l0[r] * E2(m0[r] - nm0) + E2(v0 - nm0);
      m0[r] = nm0;
      float v1 = (col1 <= q) ? c1[r] : -1e30f;        // chain 1 (independent)
      float nm1 = fmaxf(m1[r], v1);
      l1[r] = l1[r] * E2(m1[r] - nm1) + E2(v1 - nm1);
      m1[r] = nm1;
    }
  }
  float m[4], l[4];
#pragma unroll
  for (int r = 0; r < 4; ++r) {                       // merge the two chains
    float nm = fmaxf(m0[r], m1[r]);
    l[r] = l0[r] * E2(m0[r] - nm) + l1[r] * E2(m1[r] - nm);
    m[r] = nm;
  }
#pragma unroll
  for (int r = 0; r < 4; ++r) {                       // width-16 lane merge
#pragma unroll
    for (int off = 1; off < 16; off <<= 1) {
      float om = __shfl_xor(m[r], off, 16);
      float ol = __shfl_xor(l[r], off, 16);
      float nm = fmaxf(m[r], om);
      l[r] = l[r] * E2(m[r] - nm) + ol * E2(om - nm);
      m[r] = nm;
    }
  }
  float rl[4];
#pragma unroll
  for (int r = 0; r < 4; ++r) rl[r] = 1.f / l[r];

  // ---- pass 2 -------------------------------------------------------------
  f32x4 oacc[4];
#pragma unroll
  for (int s4 = 0; s4 < 4; ++s4) oacc[s4] = (f32x4){0.f, 0.f, 0.f, 0.f};
  float* pf = &Pf[w][0];
  const u16* vtb = Vt + (size_t)bh * 64 * 2048;
  float* wrow = Wout + (size_t)bh * 2048 * 2048;
  int srow = lane >> 3, scol = (lane & 7) << 2;       // coalesced store map

  int na = qmax / 32 + 1;                             // active 32-col tiles
  for (int kt2 = 0; kt2 < na; ++kt2) {
    int k0 = kt2 * 32;
    f32x4 cc[2] = {{0.f,0.f,0.f,0.f}, {0.f,0.f,0.f,0.f}};
    const u16* kr = kbase + (size_t)(k0 + l16) * 64 + quad * 8;
    bf16x8 b00 = *(const bf16x8*)(kr);
    bf16x8 b01 = *(const bf16x8*)(kr + 32);
    bf16x8 b10 = *(const bf16x8*)(kr + 1024);
    bf16x8 b11 = *(const bf16x8*)(kr + 1024 + 32);
    cc[0] = MFMA(aq0, b00, cc[0]);
    cc[0] = MFMA(aq1, b01, cc[0]);
    cc[1] = MFMA(aq0, b10, cc[1]);
    cc[1] = MFMA(aq1, b11, cc[1]);
#pragma unroll
    for (int sub = 0; sub < 2; ++sub) {
      int col = k0 + sub * 16 + l16;
#pragma unroll
      for (int r = 0; r < 4; ++r) {
        int q = q0 + quad * 4 + r;
        float p = (col <= q) ? E2(cc[sub][r] - m[r]) * rl[r] : 0.f;
        pf[(quad * 4 + r) * 36 + sub * 16 + l16] = p;
      }
    }
    // coalesced fp32 store: 2 float4/lane, 8 rows x 128B contiguous per instr
    f32x4 v0 = *(const f32x4*)(pf + srow * 36 + scol);
    f32x4 v1 = *(const f32x4*)(pf + (srow + 8) * 36 + scol);
    *(f32x4*)(wrow + (size_t)(q0 + srow) * 2048 + k0 + scol) = v0;
    *(f32x4*)(wrow + (size_t)(q0 + srow + 8) * 2048 + k0 + scol) = v1;
    // PV A-fragment from the fp32 staging (A-layout read + cvt to bf16)
    f32x4 pa0 = *(const f32x4*)(pf + l16 * 36 + quad * 8);
    f32x4 pa1 = *(const f32x4*)(pf + l16 * 36 + quad * 8 + 4);
    bf16x8 pa;
#pragma unroll
    for (int e = 0; e < 4; ++e) {
      pa[e]     = (short)f2bf(pa0[e]);
      pa[e + 4] = (short)f2bf(pa1[e]);
    }
#pragma unroll
    for (int s4 = 0; s4 < 4; ++s4) {
      const u16* vr = vtb + (size_t)(s4 * 16 + l16) * 2048 + k0 + quad * 8;
      bf16x8 bv = *(const bf16x8*)(vr);
      oacc[s4] = MFMA(pa, bv, oacc[s4]);
    }
  }
  // zero-fill the masked remainder [na*32, 2048) — 1KB per instruction
  int zstart = na * 32;
  f32x4 z = {0.f, 0.f, 0.f, 0.f};
  for (int r = 0; r < 16; ++r) {
    float* rb = wrow + (size_t)(q0 + r) * 2048;
    for (int c = zstart + (lane << 2); c < 2048; c += 256)
      *(f32x4*)(rb + c) = z;
  }
  // ctx[b][s][h*64+d]
  int b = bh >> 4, h = bh & 15;
#pragma unroll
  for (int s4 = 0; s4 < 4; ++s4)
#pragma unroll
    for (int r = 0; r < 4; ++r) {
      int q = q0 + quad * 4 + r;
      int d = s4 * 16 + l16;
      ctx[((size_t)(b * 2048 + q)) * 1024 + h * 64 + d] = f2bf(oacc[s4][r]);
    }
}

// ---------------------------------------------------------------------------
extern "C" void kernel_launch(void* const* d_in, const int* in_sizes, int n_in,
                              void* d_out, int out_size, void* d_ws, size_t ws_size,
                              hipStream_t stream) {
  const float* hs     = (const float*)d_in[0];
  const float* w_attn = (const float*)d_in[1];
  const float* b_attn = (const float*)d_in[2];
  const float* w_proj = (const float*)d_in[3];
  const float* b_proj = (const float*)d_in[4];

  char*  outc  = (char*)d_out;
  float* out_f = (float*)d_out;
  float* Wout  = out_f + 4194304;                 // weights region (512 MB)

  // scratch carved out of d_out (dead/alive windows don't overlap):
  u16* qbuf = (u16*)outc;                         // attn_out region: Q (8 MB)
  u16* kbuf = (u16*)(outc + 8388608);             //                  K (8 MB)
  u16* hsb  = (u16*)(outc + 530579456);           // weights tail: hs bf16 (8 MB)
  u16* wtA  = (u16*)(outc + 538968064);           //               w_attn^T (6 MB)
  u16* vbuf = (u16*)(outc + 545259520);           //               V (8 MB)

  char* ws  = (char*)d_ws;                        // 18 MB of d_ws used
  u16*  vt  = (u16*)ws;                           // V^T (8 MB)
  u16*  ctx = (u16*)(ws + 8388608);               // pre-proj context (8 MB)
  u16*  wtP = (u16*)(ws + 16777216);              // w_proj^T (2 MB)

  k_cast<<<4096, 256, 0, stream>>>(hs, hsb, 4194304);
  k_transpose_cast<<<dim3(48, 16), 256, 0, stream>>>(w_attn, wtA, 1024, 3072);
  k_transpose_cast<<<dim3(16, 16), 256, 0, stream>>>(w_proj, wtP, 1024, 1024);
  k_gemm_qkv<<<dim3(24, 32), 256, 0, stream>>>(hsb, wtA, b_attn, qbuf, kbuf, vbuf);
  k_transpose_v<<<dim3(32, 32), 256, 0, stream>>>(vbuf, vt);
  k_attn<<<1024, 256, 0, stream>>>(qbuf, kbuf, vt, ctx, Wout);
  k_gemm_proj<<<dim3(8, 32), 256, 0, stream>>>(ctx, wtP, b_proj, out_f);
}